// Round 10
// baseline (821.841 us; speedup 1.0000x reference)
//
#include <hip/hip_runtime.h>

// ---------------- problem constants ----------------
#define NROWS   131072
#define KDIM    1024
#define NLVL    4
#define SLOT_CAP 131584            // 131072 + 4*128 padding
#define NSB     1028               // SLOT_CAP / 128 slot-blocks
#define NNB     8                  // 1024 cols / 128

// ---------------- ws layout (bytes) ----------------
#define OFF_IDX  1024ull
#define OFF_PART (OFF_IDX + (size_t)SLOT_CAP * 4)
#define OFF_WT1  (OFF_PART + (size_t)SLOT_CAP * 64)
#define OFF_WT2  (OFF_WT1 + 8388608ull)
#define OFF_XBF  (OFF_WT2 + 8388608ull)
#define OFF_H1   (OFF_XBF + 268435456ull)
// END = OFF_H1 + SLOT_CAP*2048 = 563,645,440 bytes

typedef __bf16 bf16x8 __attribute__((ext_vector_type(8)));
typedef float f32x4 __attribute__((ext_vector_type(4)));
typedef unsigned short u16x4 __attribute__((ext_vector_type(4)));

__device__ __forceinline__ unsigned short f2bf(float f) {
  unsigned int u = __float_as_uint(f);
  u += 0x7fffu + ((u >> 16) & 1u);       // RNE
  return (unsigned short)(u >> 16);
}

__device__ __forceinline__ void gld_lds16(const void* g, void* l) {
  __builtin_amdgcn_global_load_lds(
      (const __attribute__((address_space(1))) void*)g,
      (__attribute__((address_space(3))) void*)l, 16, 0, 0);
}

// meta layout (ints): [0..3]=counts [4..7]=cursors [8..11]=seg [12..15]=padded counts

__global__ void k_hist(const int* __restrict__ levels, int n, int* __restrict__ meta) {
  __shared__ int h[NLVL];
  if (threadIdx.x < NLVL) h[threadIdx.x] = 0;
  __syncthreads();
  for (int t = blockIdx.x * blockDim.x + threadIdx.x; t < n; t += gridDim.x * blockDim.x)
    atomicAdd(&h[levels[t]], 1);
  __syncthreads();
  if (threadIdx.x < NLVL) atomicAdd(&meta[threadIdx.x], h[threadIdx.x]);
}

__global__ void k_seg(int* meta) {
  if (threadIdx.x == 0 && blockIdx.x == 0) {
    int s = 0;
    for (int l = 0; l < NLVL; ++l) {
      int pc = (meta[l] + 127) & ~127;
      meta[8 + l] = s;
      meta[12 + l] = pc;
      s += pc;
    }
  }
}

__global__ void k_scatter(const int* __restrict__ levels, int n,
                          int* __restrict__ meta, int* __restrict__ idx) {
  __shared__ int h[NLVL], base[NLVL], cur[NLVL];
  int t = blockIdx.x * blockDim.x + threadIdx.x;
  if (threadIdx.x < NLVL) { h[threadIdx.x] = 0; cur[threadIdx.x] = 0; }
  __syncthreads();
  int lvl = 0;
  if (t < n) { lvl = levels[t]; atomicAdd(&h[lvl], 1); }
  __syncthreads();
  if (threadIdx.x < NLVL)
    base[threadIdx.x] = atomicAdd(&meta[4 + threadIdx.x], h[threadIdx.x]);
  __syncthreads();
  if (t < n) {
    int p = atomicAdd(&cur[lvl], 1);
    idx[meta[8 + lvl] + base[lvl] + p] = t;
  }
}

__global__ void k_cvt_x(const f32x4* __restrict__ x, u16x4* __restrict__ xb, int n4) {
  for (int t = blockIdx.x * blockDim.x + threadIdx.x; t < n4; t += gridDim.x * blockDim.x) {
    f32x4 v = x[t];
    u16x4 o;
    o[0] = f2bf(v[0]); o[1] = f2bf(v[1]); o[2] = f2bf(v[2]); o[3] = f2bf(v[3]);
    xb[t] = o;
  }
}

// transpose-convert W[lvl][k][n] (fp32) -> Wt[lvl][n][k] (bf16)
__global__ void k_twt(const float* __restrict__ W, unsigned short* __restrict__ Wt) {
  __shared__ float tile[32][33];
  int lvl = blockIdx.z;
  int k0 = blockIdx.x * 32, n0 = blockIdx.y * 32;
  int tx = threadIdx.x, ty = threadIdx.y;
  const float* Wp = W + (size_t)lvl * 1048576;
  unsigned short* Wtp = Wt + (size_t)lvl * 1048576;
#pragma unroll
  for (int i = 0; i < 4; ++i)
    tile[ty + i * 8][tx] = Wp[(size_t)(k0 + ty + i * 8) * 1024 + n0 + tx];
  __syncthreads();
#pragma unroll
  for (int i = 0; i < 4; ++i) {
    int nn = ty + i * 8;
    Wtp[(size_t)(n0 + nn) * 1024 + k0 + tx] = f2bf(tile[tx][nn]);
  }
}

// ---------------------------------------------------------------------------
// 128x128 grouped GEMM, BK=32, 4 waves (2m x 2n), per-wave 64x64, acc[4][4]
// f32x4, mfma 16x16x32 bf16. LDS = 2 slots x 16KB = 32KB -> **4 blocks/CU**.
// ROUND-10 RATIONALE: r3/r6/r7/r8/r9 (5 geometries, all 1 block/CU lockstep)
// are ALL pinned at 9-11 B/cy/CU staging; m97 sustained 23 B/cy with the
// same drain-per-K-step discipline but 3-4 INDEPENDENT blocks/CU. Lockstep
// barriers serialize [stage burst -> compute -> drain] CU-wide; independent
// blocks interleave anti-phase (m114 co-scheduling). 256^2 tiles force >=128
// regs/wave (acc alone) -> never >1 block; so back to the m97 regime with
// 64-AGPR waves (~120 unified regs -> 4 waves/SIMD -> 4 blocks resident).
// Phase t: STG(slot (t+1)&1, tile t+1) [4 gld] | rd wf0,xf0,wf1,xf1 | SB0 |
//   rd wf2,xf2,wf3,xf3 | lgkmcnt(4) | 4 MFMA | lgkmcnt(0) | 12 MFMA |
//   vmcnt(0) | barrier.
// Correct by construction: every phase fully drains (no counted-ledger tail
// hazards); TLP across the 4 resident blocks hides the drain latency.
// Barriers are asm s_barrier with "memory" clobber (round-4 lesson).
// Swizzle: 64B rows, 16B-chunk XOR key (row>>1)&3 on BOTH sides
// (pre-swizzled global source, linear gld_lds dest, same XOR on ds_read)
// -> conflict-free b128 reads (verified 0 conflicts rounds 7-9).
// Grid 1028 sb x 8 nb = 8224 = 32.1 blocks/CU (tail +0.1% vs r8's +12%).
// XCD-chunked bijective swizzle, nb innermost (X-tile shared by 8 nb).
// ---------------------------------------------------------------------------
#define BARRM   asm volatile("s_barrier" ::: "memory")
#define WAIT_L4 asm volatile("s_waitcnt lgkmcnt(4)" ::: "memory")
#define WAIT_L0 asm volatile("s_waitcnt lgkmcnt(0)" ::: "memory")
#define WAIT_V0 asm volatile("s_waitcnt vmcnt(0)" ::: "memory")
#define SB0     __builtin_amdgcn_sched_barrier(0)
#define PRIO(x) __builtin_amdgcn_s_setprio(x)

#define RDG1(p) { const char* w_ = lds + (p)*16384 + 8192 + offW; \
                  const char* x_ = lds + (p)*16384 + offX; \
  wf[0] = *(const bf16x8*)(w_);        xf[0] = *(const bf16x8*)(x_); \
  wf[1] = *(const bf16x8*)(w_ + 1024); xf[1] = *(const bf16x8*)(x_ + 1024); }
#define RDG2(p) { const char* w_ = lds + (p)*16384 + 8192 + offW; \
                  const char* x_ = lds + (p)*16384 + offX; \
  wf[2] = *(const bf16x8*)(w_ + 2048); xf[2] = *(const bf16x8*)(x_ + 2048); \
  wf[3] = *(const bf16x8*)(w_ + 3072); xf[3] = *(const bf16x8*)(x_ + 3072); }
#define MMA(nf_,mf_) acc[nf_][mf_] = __builtin_amdgcn_mfma_f32_16x16x32_bf16(wf[nf_], xf[mf_], acc[nf_][mf_], 0, 0, 0)
#define MMA_G1 { MMA(0,0); MMA(0,1); MMA(1,0); MMA(1,1); }
#define MMA_G2 { MMA(0,2); MMA(0,3); MMA(1,2); MMA(1,3); \
                 MMA(2,0); MMA(2,1); MMA(2,2); MMA(2,3); \
                 MMA(3,0); MMA(3,1); MMA(3,2); MMA(3,3); }
#define STG(p,t) { char* b_ = (char*)lds + (p)*16384 + (w * 2048); \
  gld_lds16(xs0 + (t)*64, b_); \
  gld_lds16(xs1 + (t)*64, b_ + 1024); \
  gld_lds16(ws0 + (t)*64, b_ + 8192); \
  gld_lds16(ws1 + (t)*64, b_ + 8192 + 1024); }

#define PHASE_CORE(p) \
  RDG1(p); SB0; RDG2(p); \
  WAIT_L4; SB0; \
  PRIO(1); MMA_G1; \
  WAIT_L0; SB0; \
  MMA_G2; PRIO(0);

template <int PASS>
__global__ __launch_bounds__(256, 4) void k_gemm(
    const unsigned short* __restrict__ Asrc,
    const unsigned short* __restrict__ Wt,
    const float* __restrict__ bias,
    const float* __restrict__ w3,
    const int* __restrict__ meta,
    const int* __restrict__ idx,
    unsigned short* __restrict__ hout,
    float* __restrict__ partial) {
  __shared__ __align__(16) char lds[32768];

  // XCD-chunked bijective swizzle over NSB*8 = 8224 blocks (8224 % 8 == 0).
  const int bid = blockIdx.x;
  const int swz = (bid & 7) * (NSB * NNB / 8) + (bid >> 3);
  const int nb = swz & 7;
  const int sb = swz >> 3;
  const int slotbase = sb * 128;
  if (slotbase >= meta[11] + meta[15]) return;
  int lvl;
  if      (slotbase < meta[9])  lvl = 0;
  else if (slotbase < meta[10]) lvl = 1;
  else if (slotbase < meta[11]) lvl = 2;
  else                          lvl = 3;

  const int tid = threadIdx.x;
  const int ln  = tid & 63;
  const int w   = tid >> 6;          // wave 0..3
  const int wm  = w >> 1;            // m-half (2 x 64 rows)
  const int wn  = w & 1;             // n-half (2 x 64 cols)
  const int l15 = ln & 15;

  // ---- staging lane constants: wave w stages rows w*32..w*32+31 (2 gld,
  //      16 rows each) of both X and W tiles ----
  const int srow = w * 32 + (ln >> 2);              // rows for gld0; gld1 +16
  const int cch  = (ln & 3) ^ ((ln >> 3) & 3);      // pre-swizzled src chunk
  int ar0, ar1;
  if (PASS == 1) { ar0 = idx[slotbase + srow]; ar1 = idx[slotbase + srow + 16]; }
  else           { ar0 = slotbase + srow;      ar1 = slotbase + srow + 16; }
  const char* xs0 = (const char*)Asrc + (size_t)ar0 * 2048 + cch * 16;
  const char* xs1 = (const char*)Asrc + (size_t)ar1 * 2048 + cch * 16;
  const char* ws0 = (const char*)Wt + ((size_t)lvl << 21)
                    + (size_t)(nb * 128 + srow) * 2048 + cch * 16;
  const char* ws1 = ws0 + 16 * 2048;

  // ---- fragment read offsets (same XOR; +16 rows = +1024B) ----
  const int xorc = ((ln >> 4) ^ ((l15 >> 1) & 3)) * 16;
  const int offX = (wm * 64 + l15) * 64 + xorc;     // + mf*1024
  const int offW = (wn * 64 + l15) * 64 + xorc;     // + nf*1024 (region +8192)

  const f32x4 vzero = {0.f, 0.f, 0.f, 0.f};
  f32x4 acc[4][4];
#pragma unroll
  for (int a = 0; a < 4; ++a)
#pragma unroll
    for (int b = 0; b < 4; ++b) acc[a][b] = vzero;
  bf16x8 wf[4], xf[4];

  // ---- prologue: stage tile 0, drain, barrier ----
  STG(0, 0);
  WAIT_V0; BARRM;

  // ---- phases 0..30: stage t+1 into other slot, compute t, drain ----
#pragma unroll
  for (int t = 0; t < 31; ++t) {
    const int p = t & 1;
    STG(p ^ 1, t + 1);
    PHASE_CORE(p);
    WAIT_V0; BARRM;
  }
  // ---- phase 31 (no staging) ----
  PHASE_CORE(1);

  // ---- epilogue ----
  const float* bv = bias + lvl * 1024;
  const int n_lo = (ln >> 4) * 4;

  if (PASS == 1) {
#pragma unroll
    for (int nf = 0; nf < 4; ++nf) {
#pragma unroll
      for (int mf = 0; mf < 4; ++mf) {
        int slot = slotbase + wm * 64 + mf * 16 + l15;
        int col = nb * 128 + wn * 64 + nf * 16 + n_lo;
        f32x4 bb = *(const f32x4*)&bv[col];
        f32x4 v = acc[nf][mf];
        u16x4 o;
#pragma unroll
        for (int r = 0; r < 4; ++r) o[r] = f2bf(fmaxf(v[r] + bb[r], 0.f));
        *(u16x4*)&hout[(size_t)slot * 1024 + col] = o;
      }
    }
  } else {
    const float* w3v = w3 + lvl * 1024;
    float ps4[4] = {0.f, 0.f, 0.f, 0.f};
#pragma unroll
    for (int mf = 0; mf < 4; ++mf) {
#pragma unroll
      for (int nf = 0; nf < 4; ++nf) {
        int col = nb * 128 + wn * 64 + nf * 16 + n_lo;
        f32x4 bb = *(const f32x4*)&bv[col];
        f32x4 ww = *(const f32x4*)&w3v[col];
        f32x4 v = acc[nf][mf];
#pragma unroll
        for (int r = 0; r < 4; ++r) ps4[mf] += fmaxf(v[r] + bb[r], 0.f) * ww[r];
      }
    }
#pragma unroll
    for (int mf = 0; mf < 4; ++mf) {
      float p = ps4[mf];
      p += __shfl_xor(p, 16);
      p += __shfl_xor(p, 32);
      if (ln < 16) {
        int slot = slotbase + wm * 64 + mf * 16 + ln;
        partial[(size_t)slot * 16 + nb * 2 + wn] = p;
      }
    }
  }
}

__global__ void k_final(const int* __restrict__ meta, const int* __restrict__ idx,
                        const float* __restrict__ partial, const float* __restrict__ b3,
                        float* __restrict__ out) {
  int t = blockIdx.x * blockDim.x + threadIdx.x;
  int total = meta[11] + meta[15];
  if (t >= total) return;
  int lvl;
  if (t < meta[9]) lvl = 0;
  else if (t < meta[10]) lvl = 1;
  else if (t < meta[11]) lvl = 2;
  else lvl = 3;
  int local = t - meta[8 + lvl];
  if (local >= meta[lvl]) return;  // padding slot
  int row = idx[t];
  const float* pp = partial + (size_t)t * 16;
  float s = 0.f;
#pragma unroll
  for (int j = 0; j < 16; ++j) s += pp[j];
  out[row] = s + b3[lvl];
}

extern "C" void kernel_launch(void* const* d_in, const int* in_sizes, int n_in,
                              void* d_out, int out_size, void* d_ws, size_t ws_size,
                              hipStream_t stream) {
  const float* x      = (const float*)d_in[0];
  const int*   levels = (const int*)d_in[1];
  const float* W1     = (const float*)d_in[2];
  const float* b1     = (const float*)d_in[3];
  const float* W2     = (const float*)d_in[4];
  const float* b2     = (const float*)d_in[5];
  const float* W3     = (const float*)d_in[6];
  const float* b3     = (const float*)d_in[7];
  float* out = (float*)d_out;

  char* ws = (char*)d_ws;
  int* meta = (int*)ws;
  int* idx = (int*)(ws + OFF_IDX);
  float* partial = (float*)(ws + OFF_PART);
  unsigned short* Wt1 = (unsigned short*)(ws + OFF_WT1);
  unsigned short* Wt2 = (unsigned short*)(ws + OFF_WT2);
  unsigned short* xb  = (unsigned short*)(ws + OFF_XBF);
  unsigned short* h1  = (unsigned short*)(ws + OFF_H1);

  // zero meta + idx (padding slots -> row 0, safe finite data)
  hipMemsetAsync(d_ws, 0, OFF_IDX + (size_t)SLOT_CAP * 4, stream);
  k_hist<<<256, 256, 0, stream>>>(levels, NROWS, meta);
  k_seg<<<1, 64, 0, stream>>>(meta);
  k_scatter<<<512, 256, 0, stream>>>(levels, NROWS, meta, idx);
  k_cvt_x<<<2048, 256, 0, stream>>>((const f32x4*)x, (u16x4*)xb, NROWS * (KDIM / 4));
  k_twt<<<dim3(32, 32, 4), dim3(32, 8), 0, stream>>>(W1, Wt1);
  k_twt<<<dim3(32, 32, 4), dim3(32, 8), 0, stream>>>(W2, Wt2);

  k_gemm<1><<<NSB * NNB, 256, 0, stream>>>(xb, Wt1, b1, nullptr, meta, idx, h1, nullptr);
  k_gemm<2><<<NSB * NNB, 256, 0, stream>>>(h1, Wt2, b2, W3, meta, idx, nullptr, partial);

  k_final<<<514, 256, 0, stream>>>(meta, idx, partial, b3, out);
}